// Round 9
// baseline (1370.671 us; speedup 1.0000x reference)
//
#include <hip/hip_runtime.h>
#include <hip/hip_bf16.h>
#include <math.h>

namespace {

constexpr int C_DIM  = 128;
constexpr int B_SZ   = 256;
constexpr int NP_OFF = 32768;
constexpr int N_TOT  = 32896;         // 257 * 128 exactly
constexpr int E_P    = 524288;
constexpr int E_NP   = 2048;
constexpr int E_TOT  = E_P + E_NP;
constexpr int WALK   = 7;
constexpr int NTR    = 257;           // 256 p-block traces + 1 np trace
constexpr int NSLICE = 8;             // channel slices (one per XCD via blockIdx%8)
constexpr int SCH    = 16;            // channels per slice (32 B bf16)

__device__ __forceinline__ float bf_lo(unsigned int w) {
  return __uint_as_float(w << 16);
}
__device__ __forceinline__ float bf_hi(unsigned int w) {
  return __uint_as_float(w & 0xffff0000u);
}

// ---------------- precompute ----------------

__global__ void init_kernel(int* __restrict__ cnt, float* __restrict__ tr,
                            float* __restrict__ u0) {
  int i = blockIdx.x * blockDim.x + threadIdx.x;
  if (i < N_TOT) { cnt[i] = 0; u0[i] = 1.0f; }
  if (i < WALK * NTR) tr[i] = 0.0f;
}

// harness delivers integer inputs as int32
__global__ void count_kernel(const int* __restrict__ ei_p,
                             const int* __restrict__ ei_np,
                             int* __restrict__ cnt) {
  int e = blockIdx.x * blockDim.x + threadIdx.x;
  if (e < E_P) {
    atomicAdd(&cnt[ei_p[E_P + e]], 1);
  } else if (e < E_TOT) {
    int i = e - E_P;
    atomicAdd(&cnt[ei_np[E_NP + i] + NP_OFF], 1);
  }
}

__global__ void dinv_kernel(const int* __restrict__ cnt, float* __restrict__ dinv,
                            int* __restrict__ fill) {
  int i = blockIdx.x * blockDim.x + threadIdx.x;
  if (i < N_TOT) {
    dinv[i] = rsqrtf((float)cnt[i] + 1.0f);  // +1 self loop
    fill[i] = 0;
  }
}

// single-block hierarchical exclusive scan of cnt -> ptr (length N_TOT+1)
__global__ void scan_kernel(const int* __restrict__ cnt, int* __restrict__ ptr) {
  const int T = 1024;
  __shared__ int part[T];
  int tid = threadIdx.x;
  const int chunk = (N_TOT + T - 1) / T;
  int begin = tid * chunk;
  int end = begin + chunk;
  if (end > N_TOT) end = N_TOT;
  if (begin > N_TOT) begin = N_TOT;
  int s = 0;
  for (int i = begin; i < end; ++i) s += cnt[i];
  part[tid] = s;
  __syncthreads();
  for (int off = 1; off < T; off <<= 1) {
    int v = (tid >= off) ? part[tid - off] : 0;
    __syncthreads();
    part[tid] += v;
    __syncthreads();
  }
  if (tid == T - 1) ptr[N_TOT] = part[T - 1];
  int run = (tid == 0) ? 0 : part[tid - 1];
  for (int i = begin; i < end; ++i) { ptr[i] = run; run += cnt[i]; }
}

// compact CSR fill: packed {src, norm_bits}
__global__ void fill_kernel(const int* __restrict__ ei_p,
                            const int* __restrict__ ei_np,
                            const int* __restrict__ ptr, int* __restrict__ fill,
                            const float* __restrict__ dinv,
                            int2* __restrict__ es) {
  int e = blockIdx.x * blockDim.x + threadIdx.x;
  int s, d;
  if (e < E_P) {
    s = ei_p[e];
    d = ei_p[E_P + e];
  } else if (e < E_TOT) {
    int i = e - E_P;
    s = ei_np[i] + NP_OFF;
    d = ei_np[E_NP + i] + NP_OFF;
  } else {
    return;
  }
  int pos = ptr[d] + atomicAdd(&fill[d], 1);
  es[pos] = make_int2(s, __float_as_int(dinv[s] * dinv[d]));
}

// A0 = round_bf16([x_p ; x_np]) in SLICED layout: slice s holds channels
// [s*16, s*16+16) as N_TOT x 32B rows (2 uint4 per node).
__global__ void concat_kernel(const float* __restrict__ x_p,
                              const float* __restrict__ x_np,
                              __hip_bfloat16* __restrict__ A0) {
  int i = blockIdx.x * blockDim.x + threadIdx.x;  // (node, c16)
  if (i >= N_TOT * 16) return;
  int node = i >> 4;
  int c16 = i & 15;
  int slice = c16 >> 1, c = c16 & 1;
  const float* src = (node < NP_OFF)
      ? (x_p + (size_t)node * C_DIM + c16 * 8)
      : (x_np + (size_t)(node - NP_OFF) * C_DIM + c16 * 8);
  union { __hip_bfloat16 h[8]; uint4 u; } pk;
#pragma unroll
  for (int j = 0; j < 8; ++j) pk.h[j] = __float2bfloat16(src[j]);
  ((uint4*)A0)[((size_t)slice * N_TOT + node) * 2 + c] = pk.u;
}

// P1 = W^T (fp32). P_t = (W^T)^t so that (W^t)[k,i] = P_t[i,k].
__global__ void wt_kernel(const float* __restrict__ W, float* __restrict__ P1) {
  int i = blockIdx.x * blockDim.x + threadIdx.x;
  if (i >= C_DIM * C_DIM) return;
  int dcol = i >> 7, k = i & 127;
  P1[i] = W[k * C_DIM + dcol];
}

// C = A @ B, 128x128x128 fp32
__global__ __launch_bounds__(128) void pgemm_kernel(const float* __restrict__ A,
                                                    const float* __restrict__ Bm,
                                                    float* __restrict__ Cm) {
  const int i = blockIdx.x;
  const int c = threadIdx.x;
  float acc = 0.0f;
  for (int m = 0; m < C_DIM; ++m) acc += A[i * C_DIM + m] * Bm[m * C_DIM + c];
  Cm[i * C_DIM + c] = acc;
}

// wvec[j] = b^T W^j  (j=0..6)
__global__ void wvec_kernel(const float* __restrict__ b,
                            const float* __restrict__ P,
                            float* __restrict__ wvec) {
  int tid = blockIdx.x * blockDim.x + threadIdx.x;
  if (tid >= WALK * C_DIM) return;
  int j = tid >> 7, i = tid & 127;
  if (j == 0) { wvec[tid] = b[i]; return; }
  const float* Pj = P + (size_t)(j - 1) * C_DIM * C_DIM;
  float s = 0.0f;
  for (int k = 0; k < C_DIM; ++k) s += b[k] * Pj[i * C_DIM + k];
  wvec[tid] = s;
}

// u_{j+1} = S u_j (16 lanes per node, compact CSR)
__global__ __launch_bounds__(256) void uchain_kernel(const float* __restrict__ u,
                                                     float* __restrict__ un,
                                                     const int* __restrict__ ptr,
                                                     const int2* __restrict__ es,
                                                     const float* __restrict__ dinv) {
  const int node = blockIdx.x * 16 + (threadIdx.x >> 4);
  const int sub = threadIdx.x & 15;
  const int e0 = ptr[node], e1 = ptr[node + 1];
  float acc = 0.0f;
  for (int e = e0 + sub; e < e1; e += 16) {
    int2 p = es[e];
    acc += __int_as_float(p.y) * u[p.x];
  }
  acc += __shfl_xor(acc, 1);
  acc += __shfl_xor(acc, 2);
  acc += __shfl_xor(acc, 4);
  acc += __shfl_xor(acc, 8);
  if (sub == 0) {
    float di = dinv[node];
    un[node] = di * di * u[node] + acc;
  }
}

// exact bias-trace convolution: tr[r][b] += sum_i sum_{j<=r} u_j[b*128+i]*wvec_{r-j}[i]
__global__ __launch_bounds__(128) void ubias_tr_kernel(const float* __restrict__ u,
                                                       const float* __restrict__ wvec,
                                                       float* __restrict__ tr) {
  __shared__ float sm[128];
  const int b = blockIdx.x;      // 0..256
  const int i = threadIdx.x;
  float uj[WALK];
#pragma unroll
  for (int j = 0; j < WALK; ++j) uj[j] = u[(size_t)j * N_TOT + b * 128 + i];
  for (int r = 0; r < WALK; ++r) {
    float s = 0.0f;
#pragma unroll
    for (int j = 0; j < WALK; ++j)
      if (j <= r) s += uj[j] * wvec[(r - j) * C_DIM + i];
    sm[i] = s;
    __syncthreads();
    for (int off = 64; off >= 1; off >>= 1) {
      if (i < off) sm[i] += sm[i + off];
      __syncthreads();
    }
    if (i == 0) atomicAdd(&tr[r * NTR + b], sm[0]);
    __syncthreads();
  }
}

// ---------------- walk step: A_t = S A_{t-1}, one channel slice ----------------
// slice = blockIdx % 8 -> all work on slice s lands on XCD s (round-robin
// dispatch): the 1.05 MB slice table is L2-resident, and the slice written
// this step is re-gathered on the SAME XCD next step (warm L2 across steps).
// Block = 8 consecutive nodes (4 waves x 2 nodes). Lane = (node:1, edge:4,
// chunk:1). Per 16-edge round: one es packet + one 16B gather per lane, all
// L2-local. es is read with NONTEMPORAL loads so the 4.2 MB stream cannot
// evict the hot slice. One trace atomic per block (all 8 nodes same tr row).
__global__ __launch_bounds__(256) void agg_step(const __hip_bfloat16* __restrict__ Asrc,
                                                __hip_bfloat16* __restrict__ Adst,
                                                const int* __restrict__ ptr,
                                                const int2* __restrict__ es,
                                                const float* __restrict__ dinv,
                                                const float* __restrict__ Pt,
                                                float* __restrict__ tr_row,
                                                int write_out) {
  __shared__ float tsm[4];
  const int slice = blockIdx.x & 7;
  const int g = blockIdx.x >> 3;         // node octet 0..4111
  const int wave = threadIdx.x >> 6;
  const int lane = threadIdx.x & 63;
  const int nl = lane >> 5;              // node within wave
  const int e = (lane >> 1) & 15;        // edge slot
  const int c = lane & 1;                // 16B chunk of the 32B slice row
  const int node = g * 8 + wave * 2 + nl;

  const uint4* __restrict__ A4 = (const uint4*)Asrc + (size_t)slice * N_TOT * 2;
  uint4* __restrict__ D4 = (uint4*)Adst + (size_t)slice * N_TOT * 2;

  const int e0 = ptr[node], e1 = ptr[node + 1];

  float acc[8];
#pragma unroll
  for (int i = 0; i < 8; ++i) acc[i] = 0.0f;

  for (int base = e0; __any(base < e1); base += 16) {
    const int idx = base + e;
    const bool v = idx < e1;
    long long pk = 0;
    if (v) pk = __builtin_nontemporal_load((const long long*)es + idx);
    const int src = (int)(unsigned int)pk;
    const float nv = __int_as_float((int)(pk >> 32));
    uint4 r = A4[(size_t)src * 2 + c];
    unsigned int w[4] = {r.x, r.y, r.z, r.w};
#pragma unroll
    for (int i = 0; i < 4; ++i) {
      acc[2 * i]     += nv * bf_lo(w[i]);
      acc[2 * i + 1] += nv * bf_hi(w[i]);
    }
  }

  // reduce over the 16 edge slots (lane bits 1..4)
#pragma unroll
  for (int i = 0; i < 8; ++i) {
    acc[i] += __shfl_xor(acc[i], 2);
    acc[i] += __shfl_xor(acc[i], 4);
    acc[i] += __shfl_xor(acc[i], 8);
    acc[i] += __shfl_xor(acc[i], 16);
  }

  float tval = 0.0f;
  if (e == 0) {   // lanes {0,1,32,33}: (node, chunk)
    const float di = dinv[node];
    const float dd = di * di;
    uint4 sv = A4[(size_t)node * 2 + c];
    unsigned int sw[4] = {sv.x, sv.y, sv.z, sv.w};
    float outv[8];
#pragma unroll
    for (int i = 0; i < 4; ++i) {
      outv[2 * i]     = dd * bf_lo(sw[i]) + acc[2 * i];
      outv[2 * i + 1] = dd * bf_hi(sw[i]) + acc[2 * i + 1];
    }
    if (write_out) {
      union { __hip_bfloat16 h[8]; uint4 u; } pk;
#pragma unroll
      for (int i = 0; i < 8; ++i) pk.h[i] = __float2bfloat16(outv[i]);
      D4[(size_t)node * 2 + c] = pk.u;
    }
    const int dcol = node & 127;
    const float* pr = Pt + (size_t)dcol * C_DIM + slice * SCH + c * 8;
    const float4 w0 = *(const float4*)pr;
    const float4 w1 = *(const float4*)(pr + 4);
    tval = outv[0] * w0.x + outv[1] * w0.y + outv[2] * w0.z + outv[3] * w0.w
         + outv[4] * w1.x + outv[5] * w1.y + outv[6] * w1.z + outv[7] * w1.w;
  }
  // combine chunk pair, then the wave's two nodes (same tr row for all 8 nodes)
  tval += __shfl_xor(tval, 1);
  tval += __shfl_xor(tval, 32);
  if (lane == 0) tsm[wave] = tval;
  __syncthreads();
  if (threadIdx.x == 0)
    atomicAdd(&tr_row[node >> 7], tsm[0] + tsm[1] + tsm[2] + tsm[3]);
}

// ---------------- epilogue ----------------

__global__ __launch_bounds__(256) void final_kernel(const float* __restrict__ tr,
                                                    const float* __restrict__ y,
                                                    const float* __restrict__ W1,
                                                    const float* __restrict__ b1,
                                                    const float* __restrict__ W2,
                                                    const float* __restrict__ b2,
                                                    float* __restrict__ out) {
  __shared__ float sm[B_SZ];
  const int b = threadIdx.x;
  const float sgn = (y[b] - 0.5f) * 2.0f;
  float vals[WALK];
#pragma unroll
  for (int t = 0; t < WALK; ++t)
    vals[t] = (tr[t * NTR + b] - tr[t * NTR + 256]) * sgn;

  for (int t = 0; t < WALK; ++t) {
    sm[b] = vals[t];
    __syncthreads();
    for (int off = 128; off >= 1; off >>= 1) {
      if (b < off) sm[b] += sm[b + off];
      __syncthreads();
    }
    float mean = sm[0] * (1.0f / 256.0f);
    __syncthreads();
    float d = vals[t] - mean;
    sm[b] = d * d;
    __syncthreads();
    for (int off = 128; off >= 1; off >>= 1) {
      if (b < off) sm[b] += sm[b + off];
      __syncthreads();
    }
    float stdv = sqrtf(sm[0] * (1.0f / 255.0f));  // ddof=1
    __syncthreads();
    vals[t] = d / stdv;
  }

  float o = b2[0];
#pragma unroll
  for (int j = 0; j < 15; ++j) {
    float a = b1[j];
#pragma unroll
    for (int t = 0; t < WALK; ++t) a += vals[t] * W1[t * 15 + j];
    o += fmaxf(a, 0.0f) * W2[j];
  }
  out[b] = 1.0f / (1.0f + expf(-o));
}

}  // namespace

extern "C" void kernel_launch(void* const* d_in, const int* in_sizes, int n_in,
                              void* d_out, int out_size, void* d_ws, size_t ws_size,
                              hipStream_t stream) {
  const float* x_p   = (const float*)d_in[0];
  const float* x_np  = (const float*)d_in[1];
  const float* y     = (const float*)d_in[2];
  const int* ei_p    = (const int*)d_in[3];   // int inputs arrive as int32
  const int* ei_np   = (const int*)d_in[4];
  const float* W_gcn = (const float*)d_in[5];
  const float* b_gcn = (const float*)d_in[6];
  const float* W1    = (const float*)d_in[7];
  const float* b1    = (const float*)d_in[8];
  const float* W2    = (const float*)d_in[9];
  const float* b2    = (const float*)d_in[10];
  float* out         = (float*)d_out;

  char* p = (char*)d_ws;
  auto alloc = [&](size_t bytes) -> void* {
    void* r = (void*)p;
    p += (bytes + 255) & ~(size_t)255;
    return r;
  };
  __hip_bfloat16* Aping = (__hip_bfloat16*)alloc((size_t)N_TOT * C_DIM * 2);
  __hip_bfloat16* Apong = (__hip_bfloat16*)alloc((size_t)N_TOT * C_DIM * 2);
  float* Pbuf  = (float*)alloc((size_t)WALK * C_DIM * C_DIM * 4);  // (W^T)^t
  float* wvec  = (float*)alloc((size_t)WALK * C_DIM * 4);
  float* ubuf  = (float*)alloc((size_t)WALK * N_TOT * 4);          // u_0..u_6
  float* dinv  = (float*)alloc((size_t)N_TOT * 4);
  int*   cnt   = (int*)alloc((size_t)N_TOT * 4);
  int*   fill  = (int*)alloc((size_t)N_TOT * 4);
  int*   ptr   = (int*)alloc((size_t)(N_TOT + 1) * 4);
  int2*  es    = (int2*)alloc((size_t)E_TOT * 8);
  float* tr    = (float*)alloc((size_t)WALK * NTR * 4);

  __hip_bfloat16* Abuf[2] = {Aping, Apong};

  // --- precompute: compact CSR + norms ---
  init_kernel<<<(N_TOT + 255) / 256, 256, 0, stream>>>(cnt, tr, ubuf);
  count_kernel<<<(E_TOT + 255) / 256, 256, 0, stream>>>(ei_p, ei_np, cnt);
  dinv_kernel<<<(N_TOT + 255) / 256, 256, 0, stream>>>(cnt, dinv, fill);
  scan_kernel<<<1, 1024, 0, stream>>>(cnt, ptr);
  fill_kernel<<<(E_TOT + 255) / 256, 256, 0, stream>>>(ei_p, ei_np, ptr, fill,
                                                       dinv, es);
  concat_kernel<<<(N_TOT * 16 + 255) / 256, 256, 0, stream>>>(x_p, x_np, Aping);

  // --- W^T powers + bias vectors ---
  wt_kernel<<<(C_DIM * C_DIM + 255) / 256, 256, 0, stream>>>(W_gcn, Pbuf);
  for (int t = 2; t <= WALK; ++t)
    pgemm_kernel<<<C_DIM, C_DIM, 0, stream>>>(
        Pbuf + (size_t)(t - 2) * C_DIM * C_DIM, Pbuf,
        Pbuf + (size_t)(t - 1) * C_DIM * C_DIM);
  wvec_kernel<<<(WALK * C_DIM + 255) / 256, 256, 0, stream>>>(b_gcn, Pbuf, wvec);

  // --- bias/u chain + exact bias-trace convolution ---
  for (int j = 1; j < WALK; ++j)
    uchain_kernel<<<N_TOT / 16, 256, 0, stream>>>(
        ubuf + (size_t)(j - 1) * N_TOT, ubuf + (size_t)j * N_TOT, ptr, es, dinv);
  ubias_tr_kernel<<<NTR, 128, 0, stream>>>(ubuf, wvec, tr);

  // --- 7 walk steps: A_t = S A_{t-1}, trace fused; 8 XCD-pinned slices ---
  for (int t = 1; t <= WALK; ++t) {
    agg_step<<<(N_TOT / 8) * NSLICE, 256, 0, stream>>>(
        Abuf[(t - 1) & 1], Abuf[t & 1], ptr, es, dinv,
        Pbuf + (size_t)(t - 1) * C_DIM * C_DIM, tr + (size_t)(t - 1) * NTR,
        (t < WALK) ? 1 : 0);
  }

  // --- standardize + MLP + sigmoid ---
  final_kernel<<<1, B_SZ, 0, stream>>>(tr, y, W1, b1, W2, b2, out);
}